// Round 16
// baseline (4741.186 us; speedup 1.0000x reference)
//
#include <hip/hip_runtime.h>
#include <math.h>

#define B_  64
#define T_  800
#define U_  64
#define V_  60
#define C_  512
#define K_  10
#define KXF 584   // f16 row: [0..2]=x, [3]=0, [4..63]=w, [64..575]=h, pad to 584
#define NWG 512
#define NTH 512
#define KQ  8     // 8 waves; wave kq: xw k [kq*8,kq*8+8) + h ch [kq*64,(kq+1)*64)
#define NB  2     // batches per group
#define GRPWG 16  // WGs per group, CONTIGUOUS bids (deadlock-safe dispatch)

typedef unsigned long long ull;
typedef _Float16 f16;
typedef _Float16 f16x2 __attribute__((ext_vector_type(2)));

// ws: ull hpair[2][B][C] (h f32 lo32, tag hi32), agent-scope ONLY (replay-safe)
__device__ __forceinline__ float sigm(float v)  { return 1.f/(1.f+__expf(-v)); }
__device__ __forceinline__ float tanhx(float v) { return 1.f - 2.f/(__expf(2.f*v)+1.f); }

__device__ __forceinline__ float dot2(f16x2 a, f16x2 b, float c) {
  return __builtin_amdgcn_fdot2(a, b, c, false);   // v_dot2_f32_f16
}
__device__ __forceinline__ f16x2 bc2(unsigned u) {
  return __builtin_bit_cast(f16x2, u);
}
__device__ __forceinline__ float wfetch(const float* __restrict__ W_ih,
                                        const float* __restrict__ W_hh,
                                        int row, int k) {
  if (k < 3)  return W_ih[row*63 + k];
  if (k == 3) return 0.f;
  if (k < 64) return W_ih[row*63 + (k-1)];
  return W_hh[row*C_ + (k-64)];
}

// 2 x 8B device-coherent loads, one vmcnt wait (MALL path)
__device__ __forceinline__ void ld2x8_mal(const ull* p0, const ull* p1,
                                          ull& r0, ull& r1) {
  asm volatile(
    "global_load_dwordx2 %0, %2, off sc0 sc1\n\t"
    "global_load_dwordx2 %1, %3, off sc0 sc1\n\t"
    "s_waitcnt vmcnt(0)"
    : "=&v"(r0), "=&v"(r1)
    : "v"(p0), "v"(p1) : "memory");
}

__global__ __launch_bounds__(NTH, 2)   // (512,2): allocator known-good (~104 VGPR)
void lstm_attn_persistent(
    const float* __restrict__ x,         // [B,T,3]
    const float* __restrict__ onehots,   // [B,U,V]
    const float* __restrict__ text_lens, // [B,1]
    const float* __restrict__ w_old,     // [B,V]
    const float* __restrict__ kappa_old, // [B,K]
    const float* __restrict__ prev_h,    // [B,C]
    const float* __restrict__ prev_c,    // [B,C]
    const float* __restrict__ W_ih,      // [4C, 63]
    const float* __restrict__ W_hh,      // [4C, C]
    const float* __restrict__ b_ih,      // [4C]
    const float* __restrict__ b_hh,      // [4C]
    const float* __restrict__ win_W,     // [30, C]
    const float* __restrict__ win_b,     // [30]
    ull* __restrict__ hpair,
    float* __restrict__ out)
{
  // one-shot agent-acquire: drop stale clean cache lines from prior replay
  __builtin_amdgcn_fence(__ATOMIC_ACQUIRE, "agent");

  const long OUT_WS  = 0;
  const long OUT_HS  = (long)B_*T_*V_;
  const long OUT_H   = OUT_HS + (long)B_*T_*C_;
  const long OUT_C   = OUT_H  + (long)B_*C_;
  const long OUT_W   = OUT_C  + (long)B_*C_;
  const long OUT_KAP = OUT_W  + (long)B_*V_;
  const long OUT_PHI = OUT_KAP+ (long)B_*K_;

  const int tid  = threadIdx.x;
  const int kq   = tid >> 6;        // wave id
  const int lane = tid & 63;
  const int bid  = blockIdx.x;
  const int grp  = bid >> 4;        // 0..31: group (2 batches), contiguous bids
  const int gblk = bid & 15;        // 0..15: 128-gate-col block / 32-ch h chunk
  const int b0   = grp * NB;

  __shared__ __align__(16) f16   hxh[NB][KXF];          // f16 staged [x|w|h]
  __shared__ __align__(16) float wbuf[NB][64];          // f32 w (scatter + outputs)
  __shared__ __align__(16) float part[KQ][NB][2][68];   // gate partials f32
  __shared__ __align__(16) float wpart[KQ][NB][68];     // window partials f32
  __shared__ float p_lds[NB][32];
  __shared__ float kap_lds[NB][12];
  __shared__ float scale_lds[NB];
  __shared__ float winb_lds[32];
  __shared__ int   ids_lds[NB][64];

  // ---- persistent registers: f16 k-packed weights, 2 gate cols per lane ----
  // Wh[s][i]: i<4 -> xw k = kq*8+2i{,+1}; i>=4 -> h k = 64 + kq*64 + 2(i-4){,+1}
  f16x2 Wh[2][36];
  float bias2[2];
  #pragma unroll
  for (int s = 0; s < 2; ++s) {
    int gp   = gblk*128 + lane + 64*s;
    int gate = gp & 3;
    int ch   = gp >> 2;
    int row  = gate*C_ + ch;
    #pragma unroll
    for (int i = 0; i < 36; ++i) {
      int k0 = (i < 4) ? (kq*8 + 2*i) : (64 + kq*64 + 2*(i-4));
      float w0 = wfetch(W_ih, W_hh, row, k0);
      float w1 = wfetch(W_ih, W_hh, row, k0 + 1);
      f16x2 p; p[0] = (f16)w0; p[1] = (f16)w1;
      Wh[s][i] = p;
    }
    bias2[s] = b_ih[row] + b_hh[row];
  }

  // window weights f16 k-packed: lanes 0..59 -> (wj=lane%30, wh=lane/30)
  const int wj = lane % 30;
  const int wh = (lane < 60) ? (lane / 30) : 0;
  f16x2 winh[16];
  #pragma unroll
  for (int i = 0; i < 16; ++i) {
    f16x2 p;
    p[0] = (f16)win_W[wj*C_ + kq*64 + wh*32 + 2*i];
    p[1] = (f16)win_W[wj*C_ + kq*64 + wh*32 + 2*i + 1];
    winh[i] = p;
  }

  // cell state: tid<64 owns (ub = tid>>5, ch = gblk*32 + (tid&31))
  const int ub    = tid >> 5;       // 0..1 when tid<64
  const int chloc = tid & 31;
  const int mych  = gblk*32 + chloc;
  float c_reg = 0.f;
  if (tid < 64) c_reg = prev_c[(long)(b0 + ub)*C_ + mych];

  // ---- preamble staging ----
  for (int i = tid; i < NB*576; i += NTH) {
    int bb = i / 576, k = i % 576;
    int b = b0 + bb;
    float v;
    if      (k < 3)  v = x[((long)b*T_ + 0)*3 + k];
    else if (k < 4)  v = 0.f;
    else if (k < 64) v = w_old[b*V_ + (k-4)];
    else             v = prev_h[(long)b*C_ + (k-64)];
    hxh[bb][k] = (f16)v;
  }
  for (int i = tid; i < NB*64; i += NTH) {
    int bb = i >> 6, j = i & 63;
    wbuf[bb][j] = (j < 60) ? w_old[(b0+bb)*V_ + j] : 0.f;
  }
  for (int i = tid; i < NB*K_; i += NTH)
    kap_lds[i/K_][i%K_] = kappa_old[(b0 + i/K_)*K_ + i%K_];
  if (tid < NB) scale_lds[tid] = (float)U_ / text_lens[b0 + tid];
  if (tid < 30) winb_lds[tid] = win_b[tid];
  for (int i = tid; i < NB*U_; i += NTH) {
    int bb = i / U_, u = i % U_;
    const float* oh = onehots + ((long)(b0+bb)*U_ + u)*V_;
    int best = 0; float bv = oh[0];
    for (int vv = 1; vv < V_; ++vv) { float q = oh[vv]; if (q > bv) { bv = q; best = vv; } }
    ids_lds[bb][u] = best;
  }
  __syncthreads();

  for (int t = 0; t < T_; ++t) {
    // ---- A: gates GEMM (aligned slices: 8 xw k + 64 h ch per wave) ----
    float acc[NB][2];
    #pragma unroll
    for (int bb = 0; bb < NB; ++bb) {
      acc[bb][0] = (kq == 0) ? bias2[0] : 0.f;
      acc[bb][1] = (kq == 0) ? bias2[1] : 0.f;
    }
    #pragma unroll
    for (int bb = 0; bb < NB; ++bb) {
      float a0 = acc[bb][0], a1 = acc[bb][1];
      {  // xw block: 8 f16 at hxh[bb][kq*8]
        uint4 hv = *(const uint4*)&hxh[bb][kq*8];
        f16x2 h0 = bc2(hv.x), h1 = bc2(hv.y), h2 = bc2(hv.z), h3 = bc2(hv.w);
        a0 = dot2(Wh[0][0], h0, a0);  a1 = dot2(Wh[1][0], h0, a1);
        a0 = dot2(Wh[0][1], h1, a0);  a1 = dot2(Wh[1][1], h1, a1);
        a0 = dot2(Wh[0][2], h2, a0);  a1 = dot2(Wh[1][2], h2, a1);
        a0 = dot2(Wh[0][3], h3, a0);  a1 = dot2(Wh[1][3], h3, a1);
      }
      const uint4* hb = (const uint4*)&hxh[bb][64 + kq*64];
      #pragma unroll
      for (int j = 0; j < 8; ++j) {                        // 64 f16 = 8 x b128
        uint4 hv = hb[j];
        f16x2 h0 = bc2(hv.x), h1 = bc2(hv.y), h2 = bc2(hv.z), h3 = bc2(hv.w);
        a0 = dot2(Wh[0][4+4*j+0], h0, a0);  a1 = dot2(Wh[1][4+4*j+0], h0, a1);
        a0 = dot2(Wh[0][4+4*j+1], h1, a0);  a1 = dot2(Wh[1][4+4*j+1], h1, a1);
        a0 = dot2(Wh[0][4+4*j+2], h2, a0);  a1 = dot2(Wh[1][4+4*j+2], h2, a1);
        a0 = dot2(Wh[0][4+4*j+3], h3, a0);  a1 = dot2(Wh[1][4+4*j+3], h3, a1);
      }
      acc[bb][0] = a0; acc[bb][1] = a1;
    }
    #pragma unroll
    for (int bb = 0; bb < NB; ++bb) {
      part[kq][bb][0][lane] = acc[bb][0];
      part[kq][bb][1][lane] = acc[bb][1];
    }
    __syncthreads();   // B: gate partials ready

    // ---- C (wave 0): cell update + tagged publish (agent scope) ----
    if (tid < 64) {
      const int sr = chloc >> 4, c4 = (chloc & 15) * 4;
      float4 s = make_float4(0.f, 0.f, 0.f, 0.f);
      #pragma unroll
      for (int q = 0; q < KQ; ++q) {
        float4 v = *(const float4*)&part[q][ub][sr][c4];
        s.x += v.x; s.y += v.y; s.z += v.z; s.w += v.w;
      }
      float ig = sigm(s.x), fg = sigm(s.y), gg = tanhx(s.z), og = sigm(s.w);
      float c = fg*c_reg + ig*gg;
      c_reg = c;
      float h = og * tanhx(c);
      int b = b0 + ub;
      ull pk = ((ull)(unsigned)(t+1) << 32) | (ull)__float_as_uint(h);
      __hip_atomic_store(&hpair[(long)(t&1)*B_*C_ + (long)b*C_ + mych], pk,
                         __ATOMIC_RELAXED, __HIP_MEMORY_SCOPE_AGENT);
      out[OUT_HS + ((long)b*T_ + t)*C_ + mych] = h;
      if (t == T_-1) {
        out[OUT_H + (long)b*C_ + mych] = h;
        out[OUT_C + (long)b*C_ + mych] = c;
      }
    }
    // no barrier: P is gated by the tags themselves

    // ---- P: per-wave poll+gather own 64-ch range (1 ch/lane, 2 batches) ----
    {
      const int want = t + 1;
      const int ch = kq*64 + lane;
      const long boff = (long)(t&1)*B_*C_ + ch;
      const ull* p0 = hpair + boff + (long)(b0+0)*C_;
      const ull* p1 = hpair + boff + (long)(b0+1)*C_;
      ull r0=0, r1=0;
      while (true) {
        ld2x8_mal(p0, p1, r0, r1);
        bool ok = (int)(r0>>32) >= want && (int)(r1>>32) >= want;
        if (__all(ok)) break;
      }
      hxh[0][64+ch] = (f16)__uint_as_float((unsigned)r0);
      hxh[1][64+ch] = (f16)__uint_as_float((unsigned)r1);
    }
    // no barrier: I reads only this wave's own gathered slice

    // ---- I: window partials (own 64-ch slice, f16 dot2) ----
    #pragma unroll
    for (int bb = 0; bb < NB; ++bb) {
      const uint4* hb = (const uint4*)&hxh[bb][64 + kq*64 + wh*32];
      float a = 0.f;
      #pragma unroll
      for (int j = 0; j < 4; ++j) {                        // 32 f16 = 4 x b128
        uint4 hv = hb[j];
        a = dot2(winh[4*j+0], bc2(hv.x), a);
        a = dot2(winh[4*j+1], bc2(hv.y), a);
        a = dot2(winh[4*j+2], bc2(hv.z), a);
        a = dot2(winh[4*j+3], bc2(hv.w), a);
      }
      if (lane < 60) wpart[kq][bb][lane] = a;
    }
    __syncthreads();   // J: window partials ready

    // ---- KM (waves 0-1, wave = batch bb): p/kappa, phi, w-scatter, x, O ----
    if (kq < NB) {
      const int bb = kq;
      if (lane < 30) {
        float s = 0.f;
        #pragma unroll
        for (int q = 0; q < KQ; ++q) s += wpart[q][bb][lane] + wpart[q][bb][30+lane];
        float p = __expf(s + winb_lds[lane]);
        p_lds[bb][lane] = p;
        if (lane >= 20) {
          float nk = kap_lds[bb][lane-20] + p;
          kap_lds[bb][lane-20] = nk;
          if (t == T_-1 && gblk == 0) out[OUT_KAP + (b0+bb)*K_ + (lane-20)] = nk;
        }
      }
      // zero w-slots (in-wave order: before adds) + stage x(t+1) f16
      if (lane < 60) wbuf[bb][lane] = 0.f;
      else if (lane < 63) {
        int tn = t + 1;
        hxh[bb][lane-60] = (f16)((tn < T_) ? x[((long)(b0+bb)*T_ + tn)*3 + (lane-60)] : 0.f);
      }
      // M: phi(u=lane) + f32 scatter
      {
        float s = 0.f;
        float uf = (float)lane;
        #pragma unroll
        for (int k = 0; k < K_; ++k) {
          float d = kap_lds[bb][k] - uf;
          s += p_lds[bb][k] * __expf(-p_lds[bb][10+k]*d*d);
        }
        float phiv = s * scale_lds[bb];
        atomicAdd(&wbuf[bb][ids_lds[bb][lane]], phiv);
        if (t == T_-1 && gblk == 0) {
          out[OUT_PHI + (b0+bb)*65 + lane] = phiv;
          if (lane == 0) {                             // phi tail u=64
            float s2 = 0.f;
            #pragma unroll
            for (int k = 0; k < K_; ++k) {
              float d = kap_lds[bb][k] - 64.f;
              s2 += p_lds[bb][k] * __expf(-p_lds[bb][10+k]*d*d);
            }
            out[OUT_PHI + (b0+bb)*65 + 64] = s2 * scale_lds[bb];
          }
        }
      }
      // f16 copy of w for next A + SPREAD ws-store (8 elements per WG)
      if (lane < 60) {
        float wv = wbuf[bb][lane];
        hxh[bb][4+lane] = (f16)wv;
        int g = bb*60 + lane;                          // 0..119 within group
        if ((g >> 3) == gblk) {                        // disjoint 8-chunk per WG
          out[OUT_WS + ((long)(b0+bb)*T_ + t)*V_ + lane] = wv;
          if (t == T_-1) out[OUT_W + (b0+bb)*V_ + lane] = wv;
        }
      }
    }
    __syncthreads();   // N: w/x ready for next A (all waves read hxh[.][0..63])
  }
}

extern "C" void kernel_launch(void* const* d_in, const int* in_sizes, int n_in,
                              void* d_out, int out_size, void* d_ws, size_t ws_size,
                              hipStream_t stream) {
  const float* x         = (const float*)d_in[0];
  const float* onehots   = (const float*)d_in[1];
  const float* text_lens = (const float*)d_in[2];
  const float* w_old     = (const float*)d_in[3];
  const float* kappa_old = (const float*)d_in[4];
  const float* prev_h    = (const float*)d_in[5];
  const float* prev_c    = (const float*)d_in[6];
  const float* W_ih      = (const float*)d_in[7];
  const float* W_hh      = (const float*)d_in[8];
  const float* b_ih      = (const float*)d_in[9];
  const float* b_hh      = (const float*)d_in[10];
  const float* win_W     = (const float*)d_in[11];
  const float* win_b     = (const float*)d_in[12];
  ull*   hpair = (ull*)d_ws;
  float* out   = (float*)d_out;

  // zero the tagged region (stale tags from prior replay must read < 1)
  hipMemsetAsync(d_ws, 0, 2ull*B_*C_*sizeof(ull), stream);

  lstm_attn_persistent<<<NWG, NTH, 0, stream>>>(
      x, onehots, text_lens, w_old, kappa_old, prev_h, prev_c,
      W_ih, W_hh, b_ih, b_hh, win_W, win_b, hpair, out);
}

// Round 17
// 3537.828 us; speedup vs baseline: 1.3401x; 1.3401x over previous
//
#include <hip/hip_runtime.h>
#include <math.h>

#define B_  64
#define T_  800
#define U_  64
#define V_  60
#define C_  512
#define K_  10
#define KXF 584   // f16 row: [0..2]=x, [3]=0, [4..63]=w, [64..575]=h, pad to 584
#define NWG 256
#define NTH 512
#define KQ  8     // 8 waves; wave kq: xw k [kq*8,kq*8+8) + h ch [kq*64,(kq+1)*64)
#define NB  4     // batches per group
#define GRPWG 16  // WGs per group
#define CP  256   // C/2 packed ch-pair slots per batch

typedef unsigned long long ull;
typedef _Float16 f16;
typedef _Float16 f16x2 __attribute__((ext_vector_type(2)));

// ws: ull hpair[2][B][CP]  (tag32 hi | f16 h[2c+1] | f16 h[2c]), agent-scope ONLY
__device__ __forceinline__ float sigm(float v)  { return 1.f/(1.f+__expf(-v)); }
__device__ __forceinline__ float tanhx(float v) { return 1.f - 2.f/(__expf(2.f*v)+1.f); }

__device__ __forceinline__ float dot2(f16x2 a, f16x2 b, float c) {
  return __builtin_amdgcn_fdot2(a, b, c, false);   // v_dot2_f32_f16
}
__device__ __forceinline__ f16x2 bc2(unsigned u) {
  return __builtin_bit_cast(f16x2, u);
}
__device__ __forceinline__ float wfetch(const float* __restrict__ W_ih,
                                        const float* __restrict__ W_hh,
                                        int row, int k) {
  if (k < 3)  return W_ih[row*63 + k];
  if (k == 3) return 0.f;
  if (k < 64) return W_ih[row*63 + (k-1)];
  return W_hh[row*C_ + (k-64)];
}

// 2 x 8B device-coherent loads, one vmcnt wait (MALL path)
__device__ __forceinline__ void ld2x8_mal(const ull* p0, const ull* p1,
                                          ull& r0, ull& r1) {
  asm volatile(
    "global_load_dwordx2 %0, %2, off sc0 sc1\n\t"
    "global_load_dwordx2 %1, %3, off sc0 sc1\n\t"
    "s_waitcnt vmcnt(0)"
    : "=&v"(r0), "=&v"(r1)
    : "v"(p0), "v"(p1) : "memory");
}

__global__ __launch_bounds__(NTH, 2)
void lstm_attn_persistent(
    const float* __restrict__ x,         // [B,T,3]
    const float* __restrict__ onehots,   // [B,U,V]
    const float* __restrict__ text_lens, // [B,1]
    const float* __restrict__ w_old,     // [B,V]
    const float* __restrict__ kappa_old, // [B,K]
    const float* __restrict__ prev_h,    // [B,C]
    const float* __restrict__ prev_c,    // [B,C]
    const float* __restrict__ W_ih,      // [4C, 63]
    const float* __restrict__ W_hh,      // [4C, C]
    const float* __restrict__ b_ih,      // [4C]
    const float* __restrict__ b_hh,      // [4C]
    const float* __restrict__ win_W,     // [30, C]
    const float* __restrict__ win_b,     // [30]
    ull* __restrict__ hpair,
    float* __restrict__ out)
{
  // one-shot agent-acquire: drop stale clean cache lines from prior replay
  __builtin_amdgcn_fence(__ATOMIC_ACQUIRE, "agent");

  const long OUT_WS  = 0;
  const long OUT_HS  = (long)B_*T_*V_;
  const long OUT_H   = OUT_HS + (long)B_*T_*C_;
  const long OUT_C   = OUT_H  + (long)B_*C_;
  const long OUT_W   = OUT_C  + (long)B_*C_;
  const long OUT_KAP = OUT_W  + (long)B_*V_;
  const long OUT_PHI = OUT_KAP+ (long)B_*K_;

  const int tid  = threadIdx.x;
  const int kq   = tid >> 6;        // wave id
  const int lane = tid & 63;
  const int bid  = blockIdx.x;
  const int grp  = bid & 15;        // group (4 batches)
  const int gblk = bid >> 4;        // 0..15: 128-gate-col block / 32-ch h chunk
  const int b0   = grp * NB;

  __shared__ __align__(16) f16   hxh[NB][KXF];          // f16 staged [x|w|h]
  __shared__ __align__(16) float wbuf[NB][64];          // f32 w (scatter + outputs)
  __shared__ __align__(16) float part[KQ][NB][2][68];   // gate partials f32
  __shared__ __align__(16) float wpart[KQ][NB][68];     // window partials f32
  __shared__ float p_lds[NB][32];
  __shared__ float kap_lds[NB][12];
  __shared__ float scale_lds[NB];
  __shared__ float winb_lds[32];
  __shared__ int   ids_lds[NB][64];

  // ---- persistent registers: f16 k-packed weights, 2 gate cols per lane ----
  // Wh[s][i]: i<4 -> xw k = kq*8+2i{,+1}; i>=4 -> h k = 64 + kq*64 + 2(i-4){,+1}
  f16x2 Wh[2][36];
  float bias2[2];
  #pragma unroll
  for (int s = 0; s < 2; ++s) {
    int gp   = gblk*128 + lane + 64*s;
    int gate = gp & 3;
    int ch   = gp >> 2;
    int row  = gate*C_ + ch;
    #pragma unroll
    for (int i = 0; i < 36; ++i) {
      int k0 = (i < 4) ? (kq*8 + 2*i) : (64 + kq*64 + 2*(i-4));
      float w0 = wfetch(W_ih, W_hh, row, k0);
      float w1 = wfetch(W_ih, W_hh, row, k0 + 1);
      f16x2 p; p[0] = (f16)w0; p[1] = (f16)w1;
      Wh[s][i] = p;
    }
    bias2[s] = b_ih[row] + b_hh[row];
  }

  // window weights f16 k-packed: lanes 0..59 -> (wj=lane%30, wh=lane/30)
  const int wj = lane % 30;
  const int wh = (lane < 60) ? (lane / 30) : 0;
  f16x2 winh[16];
  #pragma unroll
  for (int i = 0; i < 16; ++i) {
    f16x2 p;
    p[0] = (f16)win_W[wj*C_ + kq*64 + wh*32 + 2*i];
    p[1] = (f16)win_W[wj*C_ + kq*64 + wh*32 + 2*i + 1];
    winh[i] = p;
  }

  // cell state: tid<128 owns (ub = tid>>5, ch = gblk*32 + (tid&31))
  const int ub    = tid >> 5;
  const int chloc = tid & 31;
  const int mych  = gblk*32 + chloc;
  float c_reg = 0.f;
  if (tid < 128) c_reg = prev_c[(long)(b0 + ub)*C_ + mych];

  // ---- preamble staging ----
  for (int i = tid; i < NB*576; i += NTH) {
    int bb = i / 576, k = i % 576;
    int b = b0 + bb;
    float v;
    if      (k < 3)  v = x[((long)b*T_ + 0)*3 + k];
    else if (k < 4)  v = 0.f;
    else if (k < 64) v = w_old[b*V_ + (k-4)];
    else             v = prev_h[(long)b*C_ + (k-64)];
    hxh[bb][k] = (f16)v;
  }
  for (int i = tid; i < NB*64; i += NTH) {
    int bb = i >> 6, j = i & 63;
    wbuf[bb][j] = (j < 60) ? w_old[(b0+bb)*V_ + j] : 0.f;
  }
  for (int i = tid; i < NB*K_; i += NTH)
    kap_lds[i/K_][i%K_] = kappa_old[(b0 + i/K_)*K_ + i%K_];
  if (tid < NB) scale_lds[tid] = (float)U_ / text_lens[b0 + tid];
  if (tid < 30) winb_lds[tid] = win_b[tid];
  for (int i = tid; i < NB*U_; i += NTH) {
    int bb = i / U_, u = i % U_;
    const float* oh = onehots + ((long)(b0+bb)*U_ + u)*V_;
    int best = 0; float bv = oh[0];
    for (int vv = 1; vv < V_; ++vv) { float q = oh[vv]; if (q > bv) { bv = q; best = vv; } }
    ids_lds[bb][u] = best;
  }
  __syncthreads();

  for (int t = 0; t < T_; ++t) {
    // ---- A: gates GEMM (aligned slices: 8 xw k + 64 h ch per wave) ----
    float acc[NB][2];
    #pragma unroll
    for (int bb = 0; bb < NB; ++bb) {
      acc[bb][0] = (kq == 0) ? bias2[0] : 0.f;
      acc[bb][1] = (kq == 0) ? bias2[1] : 0.f;
    }
    #pragma unroll
    for (int bb = 0; bb < NB; ++bb) {
      float a0 = acc[bb][0], a1 = acc[bb][1];
      {  // xw block: 8 f16 at hxh[bb][kq*8]
        uint4 hv = *(const uint4*)&hxh[bb][kq*8];
        f16x2 h0 = bc2(hv.x), h1 = bc2(hv.y), h2 = bc2(hv.z), h3 = bc2(hv.w);
        a0 = dot2(Wh[0][0], h0, a0);  a1 = dot2(Wh[1][0], h0, a1);
        a0 = dot2(Wh[0][1], h1, a0);  a1 = dot2(Wh[1][1], h1, a1);
        a0 = dot2(Wh[0][2], h2, a0);  a1 = dot2(Wh[1][2], h2, a1);
        a0 = dot2(Wh[0][3], h3, a0);  a1 = dot2(Wh[1][3], h3, a1);
      }
      const uint4* hb = (const uint4*)&hxh[bb][64 + kq*64];
      #pragma unroll
      for (int j = 0; j < 8; ++j) {                        // 64 f16 = 8 x b128
        uint4 hv = hb[j];
        f16x2 h0 = bc2(hv.x), h1 = bc2(hv.y), h2 = bc2(hv.z), h3 = bc2(hv.w);
        a0 = dot2(Wh[0][4+4*j+0], h0, a0);  a1 = dot2(Wh[1][4+4*j+0], h0, a1);
        a0 = dot2(Wh[0][4+4*j+1], h1, a0);  a1 = dot2(Wh[1][4+4*j+1], h1, a1);
        a0 = dot2(Wh[0][4+4*j+2], h2, a0);  a1 = dot2(Wh[1][4+4*j+2], h2, a1);
        a0 = dot2(Wh[0][4+4*j+3], h3, a0);  a1 = dot2(Wh[1][4+4*j+3], h3, a1);
      }
      acc[bb][0] = a0; acc[bb][1] = a1;
    }
    #pragma unroll
    for (int bb = 0; bb < NB; ++bb) {
      part[kq][bb][0][lane] = acc[bb][0];
      part[kq][bb][1][lane] = acc[bb][1];
    }
    __syncthreads();   // B: gate partials ready

    // ---- C (waves 0-1): cell update + PACKED tagged publish (agent scope) ----
    if (tid < 128) {
      const int sr = chloc >> 4, c4 = (chloc & 15) * 4;
      float4 s = make_float4(0.f, 0.f, 0.f, 0.f);
      #pragma unroll
      for (int q = 0; q < KQ; ++q) {
        float4 v = *(const float4*)&part[q][ub][sr][c4];
        s.x += v.x; s.y += v.y; s.z += v.z; s.w += v.w;
      }
      float ig = sigm(s.x), fg = sigm(s.y), gg = tanhx(s.z), og = sigm(s.w);
      float c = fg*c_reg + ig*gg;
      c_reg = c;
      float h = og * tanhx(c);
      int b = b0 + ub;
      // pack pair (ch even, ch odd) via lane shuffle; even-chloc lane stores
      unsigned hb16 = (unsigned)__builtin_bit_cast(unsigned short, (f16)h);
      unsigned other = (unsigned)__shfl_xor((int)hb16, 1, 64);
      if (!(chloc & 1)) {
        unsigned lo = hb16 | (other << 16);
        ull pk = ((ull)(unsigned)(t+1) << 32) | (ull)lo;
        __hip_atomic_store(&hpair[(long)(t&1)*B_*CP + (long)b*CP + (mych>>1)], pk,
                           __ATOMIC_RELAXED, __HIP_MEMORY_SCOPE_AGENT);
      }
      out[OUT_HS + ((long)b*T_ + t)*C_ + mych] = h;
      if (t == T_-1) {
        out[OUT_H + (long)b*C_ + mych] = h;
        out[OUT_C + (long)b*C_ + mych] = c;
      }
    }
    // no barrier: P is gated by the tags themselves

    // ---- P: per-wave poll+gather own 32 ch-pair slots (2 loads/lane) ----
    {
      const int want = t + 1;
      const int slot = kq*32 + (lane & 31);      // ch-pair slot [kq*32,(kq+1)*32)
      const int bp   = (lane >> 5) * 2;          // lanes<32: batches 0,1; else 2,3
      const long boff = (long)(t&1)*B_*CP + slot;
      const ull* p0 = hpair + boff + (long)(b0+bp+0)*CP;
      const ull* p1 = hpair + boff + (long)(b0+bp+1)*CP;
      ull r0=0, r1=0;
      while (true) {
        ld2x8_mal(p0, p1, r0, r1);
        bool ok = (int)(r0>>32) >= want && (int)(r1>>32) >= want;
        if (__all(ok)) break;
      }
      *(unsigned*)&hxh[bp+0][64 + 2*slot] = (unsigned)r0;  // 2 f16, no cvt
      *(unsigned*)&hxh[bp+1][64 + 2*slot] = (unsigned)r1;
    }
    // no barrier: I/A read only this wave's own gathered slice

    // ---- I: window partials (own 64-ch slice, f16 dot2) ----
    #pragma unroll
    for (int bb = 0; bb < NB; ++bb) {
      const uint4* hb = (const uint4*)&hxh[bb][64 + kq*64 + wh*32];
      float a = 0.f;
      #pragma unroll
      for (int j = 0; j < 4; ++j) {                        // 32 f16 = 4 x b128
        uint4 hv = hb[j];
        a = dot2(winh[4*j+0], bc2(hv.x), a);
        a = dot2(winh[4*j+1], bc2(hv.y), a);
        a = dot2(winh[4*j+2], bc2(hv.z), a);
        a = dot2(winh[4*j+3], bc2(hv.w), a);
      }
      if (lane < 60) wpart[kq][bb][lane] = a;
    }
    __syncthreads();   // J: window partials ready

    // ---- KM (waves 0-3, wave = batch bb): p/kappa, phi, w-scatter, x, O ----
    if (kq < NB) {
      const int bb = kq;
      if (lane < 30) {
        float s = 0.f;
        #pragma unroll
        for (int q = 0; q < KQ; ++q) s += wpart[q][bb][lane] + wpart[q][bb][30+lane];
        float p = __expf(s + winb_lds[lane]);
        p_lds[bb][lane] = p;
        if (lane >= 20) {
          float nk = kap_lds[bb][lane-20] + p;
          kap_lds[bb][lane-20] = nk;
          if (t == T_-1 && gblk == 0) out[OUT_KAP + (b0+bb)*K_ + (lane-20)] = nk;
        }
      }
      // zero w-slots (in-wave order: before adds) + stage x(t+1) f16
      if (lane < 60) wbuf[bb][lane] = 0.f;
      else if (lane < 63) {
        int tn = t + 1;
        hxh[bb][lane-60] = (f16)((tn < T_) ? x[((long)(b0+bb)*T_ + tn)*3 + (lane-60)] : 0.f);
      }
      // M: phi(u=lane) + f32 scatter
      {
        float s = 0.f;
        float uf = (float)lane;
        #pragma unroll
        for (int k = 0; k < K_; ++k) {
          float d = kap_lds[bb][k] - uf;
          s += p_lds[bb][k] * __expf(-p_lds[bb][10+k]*d*d);
        }
        float phiv = s * scale_lds[bb];
        atomicAdd(&wbuf[bb][ids_lds[bb][lane]], phiv);
        if (t == T_-1 && gblk == 0) {
          out[OUT_PHI + (b0+bb)*65 + lane] = phiv;
          if (lane == 0) {                             // phi tail u=64
            float s2 = 0.f;
            #pragma unroll
            for (int k = 0; k < K_; ++k) {
              float d = kap_lds[bb][k] - 64.f;
              s2 += p_lds[bb][k] * __expf(-p_lds[bb][10+k]*d*d);
            }
            out[OUT_PHI + (b0+bb)*65 + 64] = s2 * scale_lds[bb];
          }
        }
      }
      // f16 copy of w for next A + SPREAD ws-store (15 elements per WG)
      if (lane < 60) {
        float wv = wbuf[bb][lane];
        hxh[bb][4+lane] = (f16)wv;
        int g = bb*60 + lane;                          // 0..239 within group
        if (g >= gblk*15 && g < gblk*15 + 15) {        // disjoint 15-chunk per WG
          out[OUT_WS + ((long)(b0+bb)*T_ + t)*V_ + lane] = wv;
          if (t == T_-1) out[OUT_W + (b0+bb)*V_ + lane] = wv;
        }
      }
    }
    __syncthreads();   // N: w/x ready for next A (all waves read hxh[.][0..63])
  }
}

extern "C" void kernel_launch(void* const* d_in, const int* in_sizes, int n_in,
                              void* d_out, int out_size, void* d_ws, size_t ws_size,
                              hipStream_t stream) {
  const float* x         = (const float*)d_in[0];
  const float* onehots   = (const float*)d_in[1];
  const float* text_lens = (const float*)d_in[2];
  const float* w_old     = (const float*)d_in[3];
  const float* kappa_old = (const float*)d_in[4];
  const float* prev_h    = (const float*)d_in[5];
  const float* prev_c    = (const float*)d_in[6];
  const float* W_ih      = (const float*)d_in[7];
  const float* W_hh      = (const float*)d_in[8];
  const float* b_ih      = (const float*)d_in[9];
  const float* b_hh      = (const float*)d_in[10];
  const float* win_W     = (const float*)d_in[11];
  const float* win_b     = (const float*)d_in[12];
  ull*   hpair = (ull*)d_ws;
  float* out   = (float*)d_out;

  // zero the packed tagged region (stale tags from prior replay must read < 1)
  hipMemsetAsync(d_ws, 0, 2ull*B_*CP*sizeof(ull), stream);

  lstm_attn_persistent<<<NWG, NTH, 0, stream>>>(
      x, onehots, text_lens, w_old, kappa_old, prev_h, prev_c,
      W_ih, W_hh, b_ih, b_hh, win_W, win_b, hpair, out);
}